// Round 1
// baseline (50.636 us; speedup 1.0000x reference)
//
#include <hip/hip_runtime.h>

// Problem constants (from reference setup_inputs)
#define BZ    32
#define NPTS  16384
#define NSMP  4096
#define KNB   64
#define NCH   6
#define RDISC 0.05f
#define EPSV  1e-9f

// Layout: block = 256 threads = 4 waves; each wave handles 4 samples
// (16 lanes per sample, 4 neighbors per lane). Block handles 16 samples.
// Grid = 131072 / 16 = 8192 blocks.
// XCD swizzle: batch = 256 blocks; map blockIdx so XCD x processes a
// contiguous slab of samples (4 batches -> 1.6 MB of features < 4 MB L2).

__global__ __launch_bounds__(256) void pnpp_kernel(
    const float* __restrict__ feat,     // [BZ*NPTS*NCH]
    const int*   __restrict__ nk_idx,   // [BZ*NSMP*KNB]
    const float* __restrict__ nk_dist,  // [BZ*NSMP*KNB]
    const int*   __restrict__ fps_idx,  // [BZ*NSMP]
    float*       __restrict__ out)      // [BZ*NSMP*11]
{
    const int lane = threadIdx.x & 63;
    const int wid  = threadIdx.x >> 6;
    const int bid  = blockIdx.x;
    // XCD-aware swizzle: nblocks = 8192, 8 XCDs, round-robin dispatch assumed.
    const int work = (bid & 7) * (gridDim.x >> 3) + (bid >> 3); // 0..8191
    const int g = lane >> 4;   // which of 4 samples this lane serves
    const int j = lane & 15;   // sublane within sample group
    const int s = work * 16 + wid * 4 + g;   // sample id 0..131071
    const int b = s >> 12;                   // batch (NSMP = 4096)

    // Coalesced idx/dist loads: lane j covers neighbors [4j, 4j+4)
    const long kbase = (long)s * KNB + j * 4;
    const int4   idx4 = *(const int4*)  (nk_idx  + kbase);
    const float4 dst4 = *(const float4*)(nk_dist + kbase);

    // Sampled point features (uniform within 16-lane group -> broadcast)
    const int p = fps_idx[s];
    const float* fsrow = feat + (long)p * NCH;
    const float2 a01 = *(const float2*)(fsrow);
    const float2 a23 = *(const float2*)(fsrow + 2);
    const float2 a45 = *(const float2*)(fsrow + 4);
    const float fs0 = a01.x, fs1 = a01.y, fs2 = a23.x;
    const float fs3 = a23.y, fs4 = a45.x, fs5 = a45.y;
    const float nfs1 = sqrtf(fs0*fs0 + fs1*fs1 + fs2*fs2);
    const float nfs2 = sqrtf(fs3*fs3 + fs4*fs4 + fs5*fs5);

    const float* fb = feat + (long)b * (NPTS * NCH);

    float cnt = 0.f;
    float s0=0.f,s1=0.f,s2=0.f,s3=0.f,s4=0.f,s5=0.f;
    float c1=0.f, c2=0.f;
    float cr0=0.f, cr1=0.f, cr2=0.f;

    const int   idxs[4] = {idx4.x, idx4.y, idx4.z, idx4.w};
    const float dsts[4] = {dst4.x, dst4.y, dst4.z, dst4.w};

    #pragma unroll
    for (int q = 0; q < 4; ++q) {
        const float* fr = fb + (long)idxs[q] * NCH;   // 24B rows, 8B aligned
        const float2 f01 = *(const float2*)(fr);
        const float2 f23 = *(const float2*)(fr + 2);
        const float2 f45 = *(const float2*)(fr + 4);
        const float f0=f01.x, f1=f01.y, f2=f23.x, f3=f23.y, f4=f45.x, f5=f45.y;

        const float ind = (dsts[q] <= RDISC) ? 1.f : 0.f;
        cnt += ind;
        s0 += ind*f0; s1 += ind*f1; s2 += ind*f2;
        s3 += ind*f3; s4 += ind*f4; s5 += ind*f5;

        const float num1 = fs0*f0 + fs1*f1 + fs2*f2;
        const float nf1  = sqrtf(f0*f0 + f1*f1 + f2*f2);
        c1 += num1 / fmaxf(nfs1 * nf1, EPSV);

        const float num2 = fs3*f3 + fs4*f4 + fs5*f5;
        const float nf2  = sqrtf(f3*f3 + f4*f4 + f5*f5);
        c2 += num2 / fmaxf(nfs2 * nf2, EPSV);

        cr0 += fs1*f2 - fs2*f1;
        cr1 += fs2*f0 - fs0*f2;
        cr2 += fs0*f1 - fs1*f0;
    }

    // Butterfly reduce over the 16-lane group (masks < 16 stay in-group)
    #pragma unroll
    for (int m = 1; m < 16; m <<= 1) {
        cnt += __shfl_xor(cnt, m, 64);
        s0  += __shfl_xor(s0,  m, 64);
        s1  += __shfl_xor(s1,  m, 64);
        s2  += __shfl_xor(s2,  m, 64);
        s3  += __shfl_xor(s3,  m, 64);
        s4  += __shfl_xor(s4,  m, 64);
        s5  += __shfl_xor(s5,  m, 64);
        c1  += __shfl_xor(c1,  m, 64);
        c2  += __shfl_xor(c2,  m, 64);
        cr0 += __shfl_xor(cr0, m, 64);
        cr1 += __shfl_xor(cr1, m, 64);
        cr2 += __shfl_xor(cr2, m, 64);
    }

    // Final values (all 16 lanes of a group hold identical sums now)
    const float rc = 1.f / cnt;            // cnt==0 -> matches ref NaN
    const float d0 = fs0 - s0*rc, d1 = fs1 - s1*rc, d2 = fs2 - s2*rc;
    const float d3 = fs3 - s3*rc, d4 = fs4 - s4*rc, d5 = fs5 - s5*rc;
    const float inv_k = 1.f / (float)KNB;
    const float o6 = c1 * inv_k, o7 = c2 * inv_k;
    const float o8 = cr0 * inv_k, o9 = cr1 * inv_k, o10 = cr2 * inv_k;

    // Coalesced write: lanes j=0..10 each write one float -> 44 contiguous
    // floats per wave in one store instruction.
    float o = d0;
    o = (j == 1)  ? d1  : o;
    o = (j == 2)  ? d2  : o;
    o = (j == 3)  ? d3  : o;
    o = (j == 4)  ? d4  : o;
    o = (j == 5)  ? d5  : o;
    o = (j == 6)  ? o6  : o;
    o = (j == 7)  ? o7  : o;
    o = (j == 8)  ? o8  : o;
    o = (j == 9)  ? o9  : o;
    o = (j == 10) ? o10 : o;
    if (j < 11) out[(long)s * 11 + j] = o;
}

extern "C" void kernel_launch(void* const* d_in, const int* in_sizes, int n_in,
                              void* d_out, int out_size, void* d_ws, size_t ws_size,
                              hipStream_t stream) {
    const float* feat = (const float*)d_in[0];
    const int*   nki  = (const int*)  d_in[1];
    const float* nkd  = (const float*)d_in[2];
    const int*   fps  = (const int*)  d_in[3];
    float* out = (float*)d_out;

    const int total_samples = BZ * NSMP;        // 131072
    const int blocks = total_samples / 16;      // 8192
    pnpp_kernel<<<dim3(blocks), dim3(256), 0, stream>>>(feat, nki, nkd, fps, out);
}